// Round 1
// baseline (1723.232 us; speedup 1.0000x reference)
//
#include <hip/hip_runtime.h>
#include <stdint.h>

#define T_TOK 32768
#define H_DIM 576
#define I_DIM 512
#define NEXP 8

typedef __attribute__((ext_vector_type(8))) short short8;
typedef __attribute__((ext_vector_type(4))) float f32x4;
typedef __attribute__((ext_vector_type(4))) float f4;
typedef __attribute__((ext_vector_type(4))) unsigned short u16x4;

__device__ __forceinline__ unsigned short f2bf(float f) {
  union { float f; unsigned u; } v; v.f = f;
  unsigned r = (v.u + 0x7fffu + ((v.u >> 16) & 1u)) >> 16;
  return (unsigned short)r;
}

__device__ __forceinline__ void gl16(const void* g, void* l) {
  __builtin_amdgcn_global_load_lds(
      (const __attribute__((address_space(1))) unsigned*)g,
      (__attribute__((address_space(3))) unsigned*)l, 16, 0, 0);
}

// ---------------- conversions ----------------

__global__ void cvt_x_k(const float* __restrict__ x, unsigned short* __restrict__ xb) {
  size_t i = ((size_t)blockIdx.x * blockDim.x + threadIdx.x) * 4;
  f4 v = *(const f4*)(x + i);
  u16x4 o;
  o.x = f2bf(v.x); o.y = f2bf(v.y); o.z = f2bf(v.z); o.w = f2bf(v.w);
  *(u16x4*)(xb + i) = o;
}

// src [batch][R][C] fp32 -> dst [batch][C][R] bf16
__global__ void cvt_w_t(const float* __restrict__ src, unsigned short* __restrict__ dst,
                        int R, int C) {
  __shared__ float tile[32][33];
  size_t boff = (size_t)blockIdx.z * R * C;
  src += boff; dst += boff;
  int r0 = blockIdx.y * 32, c0 = blockIdx.x * 32;
  for (int i = threadIdx.y; i < 32; i += 8) {
    int r = r0 + i, c = c0 + threadIdx.x;
    tile[i][threadIdx.x] = (r < R && c < C) ? src[(size_t)r * C + c] : 0.f;
  }
  __syncthreads();
  for (int i = threadIdx.y; i < 32; i += 8) {
    int c = c0 + i, r = r0 + threadIdx.x;
    if (c < C && r < R) dst[(size_t)c * R + r] = f2bf(tile[threadIdx.x][i]);
  }
}

// ---------------- router ----------------

__global__ void router_k(const float* __restrict__ x, const float* __restrict__ rw,
                         const float* __restrict__ rb, int* __restrict__ tki,
                         float* __restrict__ tkw, int* __restrict__ counts) {
  int wave = threadIdx.x >> 6, lane = threadIdx.x & 63;
  int t = blockIdx.x * 4 + wave;
  const float* xr = x + (size_t)t * H_DIM;
  float acc[NEXP];
#pragma unroll
  for (int e = 0; e < NEXP; e++) acc[e] = 0.f;
  for (int hh = lane; hh < H_DIM; hh += 64) {
    float xv = xr[hh];
#pragma unroll
    for (int e = 0; e < NEXP; e++) acc[e] += xv * rw[hh * NEXP + e];
  }
#pragma unroll
  for (int off = 32; off; off >>= 1) {
#pragma unroll
    for (int e = 0; e < NEXP; e++) acc[e] += __shfl_xor(acc[e], off);
  }
  if (lane == 0) {
    float l[NEXP];
#pragma unroll
    for (int e = 0; e < NEXP; e++) l[e] = acc[e] + rb[e];
    int e0 = 0;
    for (int e = 1; e < NEXP; e++) if (l[e] > l[e0]) e0 = e;
    int e1 = -1;
    for (int e = 0; e < NEXP; e++) {
      if (e == e0) continue;
      if (e1 < 0 || l[e] > l[e1]) e1 = e;
    }
    float w0 = 1.f / (1.f + __expf(l[e1] - l[e0]));
    float w1 = 1.f - w0;
    tki[t * 2] = e0; tki[t * 2 + 1] = e1;
    tkw[t * 2] = w0; tkw[t * 2 + 1] = w1;
    atomicAdd(&counts[e0], 1);
    atomicAdd(&counts[e1], 1);
  }
}

__global__ void offsets_k(const int* __restrict__ counts, int* __restrict__ offs,
                          int* __restrict__ pcount, int* __restrict__ etok,
                          float* __restrict__ ew) {
  __shared__ int so[NEXP], sc[NEXP], sp[NEXP];
  if (threadIdx.x == 0) {
    int o = 0;
    for (int e = 0; e < NEXP; e++) {
      int c = counts[e];
      int p = (c + 127) & ~127;
      so[e] = o; sc[e] = c; sp[e] = p;
      offs[e] = o; pcount[e] = p;
      o += p;
    }
  }
  __syncthreads();
  for (int e = 0; e < NEXP; e++) {
    for (int i = sc[e] + (int)threadIdx.x; i < sp[e]; i += blockDim.x) {
      etok[so[e] + i] = -1;
      ew[so[e] + i] = 0.f;
    }
  }
}

__global__ void scatter_k(const int* __restrict__ tki, const float* __restrict__ tkw,
                          const int* __restrict__ offs, int* __restrict__ cursor,
                          int* __restrict__ etok, float* __restrict__ ew) {
  int t = blockIdx.x * blockDim.x + threadIdx.x;
  if (t >= T_TOK) return;
#pragma unroll
  for (int k = 0; k < 2; k++) {
    int e = tki[t * 2 + k];
    int pos = atomicAdd(&cursor[e], 1);
    int slot = offs[e] + pos;
    etok[slot] = t;
    ew[slot] = tkw[t * 2 + k];
  }
}

// ---------------- fused gate/up GEMM + silu ----------------
// A = xb gathered rows [128 x 576], B = gate_t/up_t [I][H] slices, C-> h bf16 [rows][512]
__global__ __launch_bounds__(512, 2) void gateup_k(
    const unsigned short* __restrict__ xb, const unsigned short* __restrict__ wg,
    const unsigned short* __restrict__ wu, unsigned short* __restrict__ h,
    const int* __restrict__ etok, const int* __restrict__ offs,
    const int* __restrict__ pcount, int e) {
  int pcnt = pcount ? pcount[e] : T_TOK;
  int mb = blockIdx.x;
  if (mb * 128 >= pcnt) return;
  int nb = blockIdx.y;
  __shared__ unsigned short As[128 * 32];
  __shared__ unsigned short Bg[128 * 32];
  __shared__ unsigned short Bu[128 * 32];
  int t = threadIdx.x;
  int wv = t >> 6, lane = t & 63;
  int ar = t >> 2, seg = t & 3;
  int base = offs ? offs[e] : 0;
  int m0 = mb * 128 + ar;
  int tok0;
  if (etok) {
    tok0 = etok[base + m0];
    if (tok0 < 0) tok0 = 0;
  } else {
    tok0 = m0;
  }
  const unsigned short* ga = xb + (size_t)tok0 * H_DIM + seg * 8;
  int n0 = nb * 128 + ar;  // I-col, < 512 always
  const unsigned short* gg = wg + (size_t)n0 * H_DIM + seg * 8;
  const unsigned short* gu = wu + (size_t)n0 * H_DIM + seg * 8;
  char* lA = (char*)As + wv * 1024;
  char* lG = (char*)Bg + wv * 1024;
  char* lU = (char*)Bu + wv * 1024;
  int fr = lane & 15, fq = lane >> 4;
  int wm = (wv >> 2) * 64, wn = (wv & 3) * 32;
  f32x4 accg[4][2] = {};
  f32x4 accu[4][2] = {};
  for (int k0 = 0; k0 < H_DIM; k0 += 32) {
    gl16(ga + k0, lA);
    gl16(gg + k0, lG);
    gl16(gu + k0, lU);
    __syncthreads();
    short8 a[4], g[2], u[2];
#pragma unroll
    for (int i = 0; i < 4; i++)
      a[i] = *(const short8*)&As[(wm + i * 16 + fr) * 32 + fq * 8];
#pragma unroll
    for (int j = 0; j < 2; j++) {
      g[j] = *(const short8*)&Bg[(wn + j * 16 + fr) * 32 + fq * 8];
      u[j] = *(const short8*)&Bu[(wn + j * 16 + fr) * 32 + fq * 8];
    }
#pragma unroll
    for (int i = 0; i < 4; i++)
#pragma unroll
      for (int j = 0; j < 2; j++) {
        accg[i][j] = __builtin_amdgcn_mfma_f32_16x16x32_bf16(a[i], g[j], accg[i][j], 0, 0, 0);
        accu[i][j] = __builtin_amdgcn_mfma_f32_16x16x32_bf16(a[i], u[j], accu[i][j], 0, 0, 0);
      }
    __syncthreads();
  }
#pragma unroll
  for (int i = 0; i < 4; i++)
#pragma unroll
    for (int j = 0; j < 2; j++)
#pragma unroll
      for (int r = 0; r < 4; r++) {
        int row = mb * 128 + wm + i * 16 + fq * 4 + r;
        int col = nb * 128 + wn + j * 16 + fr;
        float gv = accg[i][j][r], uv = accu[i][j][r];
        float hv = (gv / (1.f + __expf(-gv))) * uv;
        h[(size_t)row * I_DIM + col] = f2bf(hv);
      }
}

// ---------------- down GEMM ----------------
// A = h [rows][512], B = down_t [576][512], out fp32
template <int MODE>  // 0: direct store (shared), 1: scaled scatter-add (routed)
__global__ __launch_bounds__(512, 2) void down_k(
    const unsigned short* __restrict__ hbuf, const unsigned short* __restrict__ wd,
    float* __restrict__ out, const int* __restrict__ etok, const float* __restrict__ ew,
    const int* __restrict__ offs, const int* __restrict__ pcount, int e) {
  int pcnt = pcount ? pcount[e] : T_TOK;
  int mb = blockIdx.x;
  if (mb * 128 >= pcnt) return;
  int nb = blockIdx.y;
  __shared__ unsigned short As[128 * 32];
  __shared__ unsigned short Bs[128 * 32];
  int t = threadIdx.x;
  int wv = t >> 6, lane = t & 63;
  int ar = t >> 2, seg = t & 3;
  const unsigned short* ga = hbuf + (size_t)(mb * 128 + ar) * I_DIM + seg * 8;
  int n0 = nb * 128 + ar;
  if (n0 > H_DIM - 1) n0 = H_DIM - 1;
  const unsigned short* gb = wd + (size_t)n0 * I_DIM + seg * 8;
  char* lA = (char*)As + wv * 1024;
  char* lB = (char*)Bs + wv * 1024;
  int fr = lane & 15, fq = lane >> 4;
  int wm = (wv >> 2) * 64, wn = (wv & 3) * 32;
  f32x4 acc[4][2] = {};
  for (int k0 = 0; k0 < I_DIM; k0 += 32) {
    gl16(ga + k0, lA);
    gl16(gb + k0, lB);
    __syncthreads();
    short8 a[4], b[2];
#pragma unroll
    for (int i = 0; i < 4; i++)
      a[i] = *(const short8*)&As[(wm + i * 16 + fr) * 32 + fq * 8];
#pragma unroll
    for (int j = 0; j < 2; j++)
      b[j] = *(const short8*)&Bs[(wn + j * 16 + fr) * 32 + fq * 8];
#pragma unroll
    for (int i = 0; i < 4; i++)
#pragma unroll
      for (int j = 0; j < 2; j++)
        acc[i][j] = __builtin_amdgcn_mfma_f32_16x16x32_bf16(a[i], b[j], acc[i][j], 0, 0, 0);
    __syncthreads();
  }
  int base = (MODE == 1) ? offs[e] : 0;
#pragma unroll
  for (int i = 0; i < 4; i++)
#pragma unroll
    for (int j = 0; j < 2; j++)
#pragma unroll
      for (int r = 0; r < 4; r++) {
        int mloc = mb * 128 + wm + i * 16 + fq * 4 + r;
        int col = nb * 128 + wn + j * 16 + fr;
        if (col >= H_DIM) continue;
        float v = acc[i][j][r];
        if (MODE == 0) {
          out[(size_t)mloc * H_DIM + col] = v;
        } else {
          int slot = base + mloc;
          int tok = etok[slot];
          if (tok >= 0) out[(size_t)tok * H_DIM + col] += ew[slot] * v;
        }
      }
}

// ---------------- host ----------------

extern "C" void kernel_launch(void* const* d_in, const int* in_sizes, int n_in,
                              void* d_out, int out_size, void* d_ws, size_t ws_size,
                              hipStream_t stream) {
  const float* x = (const float*)d_in[0];
  const float* sgw = (const float*)d_in[1];
  const float* suw = (const float*)d_in[2];
  const float* sdw = (const float*)d_in[3];
  const float* rgw = (const float*)d_in[4];
  const float* ruw = (const float*)d_in[5];
  const float* rdw = (const float*)d_in[6];
  const float* rw = (const float*)d_in[7];
  const float* rb = (const float*)d_in[8];
  float* out = (float*)d_out;
  char* ws = (char*)d_ws;

  const size_t o_xbf = 0;                       // T*576*2 = 37,748,736
  const size_t o_w = 37748736;
  const size_t w_sg = o_w;                      // [512][576]
  const size_t w_su = o_w + 589824;
  const size_t w_sd = o_w + 1179648;            // [576][512]
  const size_t w_rg = o_w + 1769472;            // 8 x [512][576]
  const size_t w_ru = o_w + 6488064;
  const size_t w_rd = o_w + 11206656;           // 8 x [576][512]
  const size_t o_tki = o_w + 15925248;          // T*2 int
  const size_t o_tkw = o_tki + 262144;          // T*2 float
  const size_t o_meta = o_tkw + 262144;         // counts[8],cursor[8],offs[16],pcount[8]
  const size_t o_etok = o_meta + 256;           // (2T+1024) int
  const size_t o_ew = o_etok + 266240;          // (2T+1024) float
  const size_t o_h = o_ew + 266240;             // T*512*2 = 33,554,432

  unsigned short* xb = (unsigned short*)(ws + o_xbf);
  int* tki = (int*)(ws + o_tki);
  float* tkw = (float*)(ws + o_tkw);
  int* counts = (int*)(ws + o_meta);
  int* cursor = counts + 8;
  int* offs = counts + 16;
  int* pcount = counts + 32;
  int* etok = (int*)(ws + o_etok);
  float* ew = (float*)(ws + o_ew);
  unsigned short* h = (unsigned short*)(ws + o_h);

  hipMemsetAsync(ws + o_meta, 0, 256, stream);
  cvt_x_k<<<18432, 256, 0, stream>>>(x, xb);
  dim3 tb(32, 8);
  cvt_w_t<<<dim3(16, 18, 1), tb, 0, stream>>>(sgw, (unsigned short*)(ws + w_sg), 576, 512);
  cvt_w_t<<<dim3(16, 18, 1), tb, 0, stream>>>(suw, (unsigned short*)(ws + w_su), 576, 512);
  cvt_w_t<<<dim3(18, 16, 1), tb, 0, stream>>>(sdw, (unsigned short*)(ws + w_sd), 512, 576);
  cvt_w_t<<<dim3(16, 18, 8), tb, 0, stream>>>(rgw, (unsigned short*)(ws + w_rg), 576, 512);
  cvt_w_t<<<dim3(16, 18, 8), tb, 0, stream>>>(ruw, (unsigned short*)(ws + w_ru), 576, 512);
  cvt_w_t<<<dim3(18, 16, 8), tb, 0, stream>>>(rdw, (unsigned short*)(ws + w_rd), 512, 576);
  router_k<<<8192, 256, 0, stream>>>(x, rw, rb, tki, tkw, counts);
  offsets_k<<<1, 256, 0, stream>>>(counts, offs, pcount, etok, ew);
  scatter_k<<<128, 256, 0, stream>>>(tki, tkw, offs, cursor, etok, ew);

  // shared expert
  gateup_k<<<dim3(256, 4), 512, 0, stream>>>(xb, (unsigned short*)(ws + w_sg),
                                             (unsigned short*)(ws + w_su), h,
                                             nullptr, nullptr, nullptr, 0);
  down_k<0><<<dim3(256, 5), 512, 0, stream>>>(h, (unsigned short*)(ws + w_sd), out,
                                              nullptr, nullptr, nullptr, nullptr, 0);
  // routed experts, sequential (race-free RMW into out)
  for (int e = 0; e < NEXP; e++) {
    const unsigned short* wg_e = (const unsigned short*)(ws + w_rg) + (size_t)e * 294912;
    const unsigned short* wu_e = (const unsigned short*)(ws + w_ru) + (size_t)e * 294912;
    const unsigned short* wd_e = (const unsigned short*)(ws + w_rd) + (size_t)e * 294912;
    gateup_k<<<dim3(256, 4), 512, 0, stream>>>(xb, wg_e, wu_e, h, etok, offs, pcount, e);
    down_k<1><<<dim3(256, 5), 512, 0, stream>>>(h, wd_e, out, etok, ew, offs, pcount, e);
  }
}

// Round 2
// 623.694 us; speedup vs baseline: 2.7629x; 2.7629x over previous
//
#include <hip/hip_runtime.h>
#include <stdint.h>

#define T_TOK 32768
#define H_DIM 576
#define I_DIM 512
#define NEXP 8

typedef __attribute__((ext_vector_type(8))) short short8;
typedef __attribute__((ext_vector_type(4))) float f32x4;
typedef __attribute__((ext_vector_type(4))) float f4;
typedef __attribute__((ext_vector_type(4))) unsigned short u16x4;

__device__ __forceinline__ unsigned short f2bf(float f) {
  union { float f; unsigned u; } v; v.f = f;
  unsigned r = (v.u + 0x7fffu + ((v.u >> 16) & 1u)) >> 16;
  return (unsigned short)r;
}

__device__ __forceinline__ void gl16(const void* g, void* l) {
  __builtin_amdgcn_global_load_lds(
      (const __attribute__((address_space(1))) unsigned*)g,
      (__attribute__((address_space(3))) unsigned*)l, 16, 0, 0);
}

// ---------------- conversions ----------------

__global__ void cvt_x_k(const float* __restrict__ x, unsigned short* __restrict__ xb) {
  size_t i = ((size_t)blockIdx.x * blockDim.x + threadIdx.x) * 4;
  f4 v = *(const f4*)(x + i);
  u16x4 o;
  o.x = f2bf(v.x); o.y = f2bf(v.y); o.z = f2bf(v.z); o.w = f2bf(v.w);
  *(u16x4*)(xb + i) = o;
}

// src [batch][R][C] fp32 -> dst [batch][C][R] bf16
__global__ void cvt_w_t(const float* __restrict__ src, unsigned short* __restrict__ dst,
                        int R, int C) {
  __shared__ float tile[32][33];
  size_t boff = (size_t)blockIdx.z * R * C;
  src += boff; dst += boff;
  int r0 = blockIdx.y * 32, c0 = blockIdx.x * 32;
  for (int i = threadIdx.y; i < 32; i += 8) {
    int r = r0 + i, c = c0 + threadIdx.x;
    tile[i][threadIdx.x] = (r < R && c < C) ? src[(size_t)r * C + c] : 0.f;
  }
  __syncthreads();
  for (int i = threadIdx.y; i < 32; i += 8) {
    int c = c0 + i, r = r0 + threadIdx.x;
    if (c < C && r < R) dst[(size_t)c * R + r] = f2bf(tile[threadIdx.x][i]);
  }
}

// ---------------- router (thread-per-token, block-aggregated atomics) --------

__global__ __launch_bounds__(256) void router_k(
    const float* __restrict__ x, const float* __restrict__ rw,
    const float* __restrict__ rb, int* __restrict__ tki,
    float* __restrict__ tkw, int* __restrict__ counts /*stride 32*/) {
  __shared__ float lrw[H_DIM * NEXP];
  __shared__ int hist[NEXP];
  int tid = threadIdx.x;
  // stage router weights (18KB) as float4
  for (int i = tid; i < H_DIM * NEXP / 4; i += 256)
    *(f4*)&lrw[i * 4] = *(const f4*)&rw[i * 4];
  if (tid < NEXP) hist[tid] = 0;
  __syncthreads();

  int t = blockIdx.x * 256 + tid;
  const float* xr = x + (size_t)t * H_DIM;
  float acc[NEXP];
#pragma unroll
  for (int e = 0; e < NEXP; e++) acc[e] = 0.f;
  for (int h = 0; h < H_DIM; h += 4) {
    f4 xv = *(const f4*)(xr + h);
#pragma unroll
    for (int j = 0; j < 4; j++) {
      f4 w0 = *(const f4*)&lrw[(h + j) * NEXP];
      f4 w1 = *(const f4*)&lrw[(h + j) * NEXP + 4];
      float xs = xv[j];
      acc[0] += xs * w0.x; acc[1] += xs * w0.y;
      acc[2] += xs * w0.z; acc[3] += xs * w0.w;
      acc[4] += xs * w1.x; acc[5] += xs * w1.y;
      acc[6] += xs * w1.z; acc[7] += xs * w1.w;
    }
  }
#pragma unroll
  for (int e = 0; e < NEXP; e++) acc[e] += rb[e];
  int e0 = 0;
#pragma unroll
  for (int e = 1; e < NEXP; e++) if (acc[e] > acc[e0]) e0 = e;
  int e1 = -1;
#pragma unroll
  for (int e = 0; e < NEXP; e++) {
    if (e == e0) continue;
    if (e1 < 0 || acc[e] > acc[e1]) e1 = e;
  }
  float w0 = 1.f / (1.f + __expf(acc[e1] - acc[e0]));
  tki[t * 2] = e0; tki[t * 2 + 1] = e1;
  tkw[t * 2] = w0; tkw[t * 2 + 1] = 1.f - w0;
  atomicAdd(&hist[e0], 1);
  atomicAdd(&hist[e1], 1);
  __syncthreads();
  if (tid < NEXP) atomicAdd(&counts[tid * 32], hist[tid]);
}

__global__ void offsets_k(const int* __restrict__ counts, int* __restrict__ offs,
                          int* __restrict__ pcount) {
  if (threadIdx.x == 0) {
    int o = 0;
    for (int e = 0; e < NEXP; e++) {
      int c = counts[e * 32];
      int p = (c + 127) & ~127;
      offs[e] = o; pcount[e] = p;
      o += p;
    }
  }
}

// block-reserved scatter: 8 global atomics per block
__global__ __launch_bounds__(256) void scatter_k(
    const int* __restrict__ tki, const float* __restrict__ tkw,
    const int* __restrict__ offs, int* __restrict__ cursor /*stride 32*/,
    int* __restrict__ etok, float* __restrict__ ew) {
  __shared__ int hist[NEXP], base[NEXP], lcur[NEXP];
  int tid = threadIdx.x;
  if (tid < NEXP) { hist[tid] = 0; lcur[tid] = 0; }
  __syncthreads();
  int t = blockIdx.x * 256 + tid;
  int e0 = tki[t * 2], e1 = tki[t * 2 + 1];
  atomicAdd(&hist[e0], 1);
  atomicAdd(&hist[e1], 1);
  __syncthreads();
  if (tid < NEXP) base[tid] = atomicAdd(&cursor[tid * 32], hist[tid]);
  __syncthreads();
#pragma unroll
  for (int k = 0; k < 2; k++) {
    int e = (k == 0) ? e0 : e1;
    int r = atomicAdd(&lcur[e], 1);
    int slot = offs[e] + base[e] + r;
    etok[slot] = t;
    ew[slot] = tkw[t * 2 + k];
  }
}

// ---------------- fused gate/up GEMM + silu ----------------
// LDS bank-conflict fix (T2 / rule #21): global_load_lds writes linearly, so we
// pre-swizzle the per-lane GLOBAL source segment sg = seg ^ ((row>>1)&3) and
// apply the same XOR on the ds_read side. Spreads a 16-lane fragment read
// across all 8 bank-groups (was 8-way conflict).
__global__ __launch_bounds__(512, 2) void gateup_k(
    const unsigned short* __restrict__ xb, const unsigned short* __restrict__ wg,
    const unsigned short* __restrict__ wu, unsigned short* __restrict__ h,
    const int* __restrict__ etok, const int* __restrict__ offs,
    const int* __restrict__ pcount, int e) {
  int pcnt = pcount ? pcount[e] : T_TOK;
  int mb = blockIdx.x;
  if (mb * 128 >= pcnt) return;
  int nb = blockIdx.y;
  __shared__ unsigned short As[128 * 32];
  __shared__ unsigned short Bg[128 * 32];
  __shared__ unsigned short Bu[128 * 32];
  int t = threadIdx.x;
  int wv = t >> 6, lane = t & 63;
  int ar = t >> 2, seg = t & 3;
  int sg = seg ^ ((ar >> 1) & 3);  // swizzled source segment
  int base = offs ? offs[e] : 0;
  int m0 = mb * 128 + ar;
  int tok0;
  if (etok) {
    tok0 = etok[base + m0];
    if (tok0 < 0) tok0 = 0;
  } else {
    tok0 = m0;
  }
  const unsigned short* ga = xb + (size_t)tok0 * H_DIM + sg * 8;
  int n0 = nb * 128 + ar;  // I-col, < 512 always
  const unsigned short* gg = wg + (size_t)n0 * H_DIM + sg * 8;
  const unsigned short* gu = wu + (size_t)n0 * H_DIM + sg * 8;
  char* lA = (char*)As + wv * 1024;
  char* lG = (char*)Bg + wv * 1024;
  char* lU = (char*)Bu + wv * 1024;
  int fr = lane & 15, fq = lane >> 4;
  int wm = (wv >> 2) * 64, wn = (wv & 3) * 32;
  f32x4 accg[4][2] = {};
  f32x4 accu[4][2] = {};
  for (int k0 = 0; k0 < H_DIM; k0 += 32) {
    gl16(ga + k0, lA);
    gl16(gg + k0, lG);
    gl16(gu + k0, lU);
    __syncthreads();
    short8 a[4], g[2], u[2];
#pragma unroll
    for (int i = 0; i < 4; i++) {
      int r = wm + i * 16 + fr;
      a[i] = *(const short8*)&As[r * 32 + (fq ^ ((r >> 1) & 3)) * 8];
    }
#pragma unroll
    for (int j = 0; j < 2; j++) {
      int r = wn + j * 16 + fr;
      int sw = (fq ^ ((r >> 1) & 3)) * 8;
      g[j] = *(const short8*)&Bg[r * 32 + sw];
      u[j] = *(const short8*)&Bu[r * 32 + sw];
    }
#pragma unroll
    for (int i = 0; i < 4; i++)
#pragma unroll
      for (int j = 0; j < 2; j++) {
        accg[i][j] = __builtin_amdgcn_mfma_f32_16x16x32_bf16(a[i], g[j], accg[i][j], 0, 0, 0);
        accu[i][j] = __builtin_amdgcn_mfma_f32_16x16x32_bf16(a[i], u[j], accu[i][j], 0, 0, 0);
      }
    __syncthreads();
  }
#pragma unroll
  for (int i = 0; i < 4; i++)
#pragma unroll
    for (int j = 0; j < 2; j++)
#pragma unroll
      for (int r = 0; r < 4; r++) {
        int row = mb * 128 + wm + i * 16 + fq * 4 + r;
        int col = nb * 128 + wn + j * 16 + fr;
        float gv = accg[i][j][r], uv = accu[i][j][r];
        float hv = (gv / (1.f + __expf(-gv))) * uv;
        h[(size_t)row * I_DIM + col] = f2bf(hv);
      }
}

// ---------------- down GEMM ----------------
template <int MODE>  // 0: direct store (shared), 1: scaled scatter-add (routed)
__global__ __launch_bounds__(512, 2) void down_k(
    const unsigned short* __restrict__ hbuf, const unsigned short* __restrict__ wd,
    float* __restrict__ out, const int* __restrict__ etok, const float* __restrict__ ew,
    const int* __restrict__ offs, const int* __restrict__ pcount, int e) {
  int pcnt = pcount ? pcount[e] : T_TOK;
  int mb = blockIdx.x;
  if (mb * 128 >= pcnt) return;
  int nb = blockIdx.y;
  __shared__ unsigned short As[128 * 32];
  __shared__ unsigned short Bs[128 * 32];
  int t = threadIdx.x;
  int wv = t >> 6, lane = t & 63;
  int ar = t >> 2, seg = t & 3;
  int sg = seg ^ ((ar >> 1) & 3);
  const unsigned short* ga = hbuf + (size_t)(mb * 128 + ar) * I_DIM + sg * 8;
  int n0 = nb * 128 + ar;
  if (n0 > H_DIM - 1) n0 = H_DIM - 1;
  const unsigned short* gb = wd + (size_t)n0 * I_DIM + sg * 8;
  char* lA = (char*)As + wv * 1024;
  char* lB = (char*)Bs + wv * 1024;
  int fr = lane & 15, fq = lane >> 4;
  int wm = (wv >> 2) * 64, wn = (wv & 3) * 32;
  f32x4 acc[4][2] = {};
  for (int k0 = 0; k0 < I_DIM; k0 += 32) {
    gl16(ga + k0, lA);
    gl16(gb + k0, lB);
    __syncthreads();
    short8 a[4], b[2];
#pragma unroll
    for (int i = 0; i < 4; i++) {
      int r = wm + i * 16 + fr;
      a[i] = *(const short8*)&As[r * 32 + (fq ^ ((r >> 1) & 3)) * 8];
    }
#pragma unroll
    for (int j = 0; j < 2; j++) {
      int r = wn + j * 16 + fr;
      b[j] = *(const short8*)&Bs[r * 32 + (fq ^ ((r >> 1) & 3)) * 8];
    }
#pragma unroll
    for (int i = 0; i < 4; i++)
#pragma unroll
      for (int j = 0; j < 2; j++)
        acc[i][j] = __builtin_amdgcn_mfma_f32_16x16x32_bf16(a[i], b[j], acc[i][j], 0, 0, 0);
    __syncthreads();
  }
  int base = (MODE == 1) ? offs[e] : 0;
#pragma unroll
  for (int i = 0; i < 4; i++)
#pragma unroll
    for (int j = 0; j < 2; j++)
#pragma unroll
      for (int r = 0; r < 4; r++) {
        int mloc = mb * 128 + wm + i * 16 + fq * 4 + r;
        int col = nb * 128 + wn + j * 16 + fr;
        if (col >= H_DIM) continue;
        float v = acc[i][j][r];
        if (MODE == 0) {
          out[(size_t)mloc * H_DIM + col] = v;
        } else {
          int slot = base + mloc;
          int tok = etok[slot];
          if (tok >= 0) out[(size_t)tok * H_DIM + col] += ew[slot] * v;
        }
      }
}

// ---------------- host ----------------

extern "C" void kernel_launch(void* const* d_in, const int* in_sizes, int n_in,
                              void* d_out, int out_size, void* d_ws, size_t ws_size,
                              hipStream_t stream) {
  const float* x = (const float*)d_in[0];
  const float* sgw = (const float*)d_in[1];
  const float* suw = (const float*)d_in[2];
  const float* sdw = (const float*)d_in[3];
  const float* rgw = (const float*)d_in[4];
  const float* ruw = (const float*)d_in[5];
  const float* rdw = (const float*)d_in[6];
  const float* rw = (const float*)d_in[7];
  const float* rb = (const float*)d_in[8];
  float* out = (float*)d_out;
  char* ws = (char*)d_ws;

  const size_t o_xbf = 0;                       // T*576*2 = 37,748,736
  const size_t o_w = 37748736;
  const size_t w_sg = o_w;                      // [512][576]
  const size_t w_su = o_w + 589824;
  const size_t w_sd = o_w + 1179648;            // [576][512]
  const size_t w_rg = o_w + 1769472;            // 8 x [512][576]
  const size_t w_ru = o_w + 6488064;
  const size_t w_rd = o_w + 11206656;           // 8 x [576][512]
  const size_t o_tki = o_w + 15925248;          // T*2 int
  const size_t o_tkw = o_tki + 262144;          // T*2 float
  const size_t o_meta = o_tkw + 262144;         // counts[8*32],cursor[8*32],offs[8],pcount[8]
  const size_t o_etok = o_meta + 4096;          // (2T+1024) int
  const size_t o_ew = o_etok + 266240;          // (2T+1024) float
  const size_t o_h = o_ew + 266240;             // T*512*2 = 33,554,432

  unsigned short* xb = (unsigned short*)(ws + o_xbf);
  int* tki = (int*)(ws + o_tki);
  float* tkw = (float*)(ws + o_tkw);
  int* counts = (int*)(ws + o_meta);            // stride-32 padded
  int* cursor = counts + 256;                   // stride-32 padded
  int* offs = counts + 512;
  int* pcount = counts + 520;
  int* etok = (int*)(ws + o_etok);
  float* ew = (float*)(ws + o_ew);
  unsigned short* h = (unsigned short*)(ws + o_h);

  hipMemsetAsync(ws + o_meta, 0, 4096, stream);
  hipMemsetAsync(etok, 0xFF, 266240, stream);   // all -1 (pad tokens)
  hipMemsetAsync(ew, 0, 266240, stream);        // pad weights 0
  cvt_x_k<<<18432, 256, 0, stream>>>(x, xb);
  dim3 tb(32, 8);
  cvt_w_t<<<dim3(16, 18, 1), tb, 0, stream>>>(sgw, (unsigned short*)(ws + w_sg), 576, 512);
  cvt_w_t<<<dim3(16, 18, 1), tb, 0, stream>>>(suw, (unsigned short*)(ws + w_su), 576, 512);
  cvt_w_t<<<dim3(18, 16, 1), tb, 0, stream>>>(sdw, (unsigned short*)(ws + w_sd), 512, 576);
  cvt_w_t<<<dim3(16, 18, 8), tb, 0, stream>>>(rgw, (unsigned short*)(ws + w_rg), 576, 512);
  cvt_w_t<<<dim3(16, 18, 8), tb, 0, stream>>>(ruw, (unsigned short*)(ws + w_ru), 576, 512);
  cvt_w_t<<<dim3(18, 16, 8), tb, 0, stream>>>(rdw, (unsigned short*)(ws + w_rd), 512, 576);
  router_k<<<128, 256, 0, stream>>>(x, rw, rb, tki, tkw, counts);
  offsets_k<<<1, 64, 0, stream>>>(counts, offs, pcount);
  scatter_k<<<128, 256, 0, stream>>>(tki, tkw, offs, cursor, etok, ew);

  // shared expert
  gateup_k<<<dim3(256, 4), 512, 0, stream>>>(xb, (unsigned short*)(ws + w_sg),
                                             (unsigned short*)(ws + w_su), h,
                                             nullptr, nullptr, nullptr, 0);
  down_k<0><<<dim3(256, 5), 512, 0, stream>>>(h, (unsigned short*)(ws + w_sd), out,
                                              nullptr, nullptr, nullptr, nullptr, 0);
  // routed experts, sequential (race-free RMW into out)
  for (int e = 0; e < NEXP; e++) {
    const unsigned short* wg_e = (const unsigned short*)(ws + w_rg) + (size_t)e * 294912;
    const unsigned short* wu_e = (const unsigned short*)(ws + w_ru) + (size_t)e * 294912;
    const unsigned short* wd_e = (const unsigned short*)(ws + w_rd) + (size_t)e * 294912;
    gateup_k<<<dim3(256, 4), 512, 0, stream>>>(xb, wg_e, wu_e, h, etok, offs, pcount, e);
    down_k<1><<<dim3(256, 5), 512, 0, stream>>>(h, wd_e, out, etok, ew, offs, pcount, e);
  }
}

// Round 3
// 418.816 us; speedup vs baseline: 4.1145x; 1.4892x over previous
//
#include <hip/hip_runtime.h>
#include <stdint.h>

#define T_TOK 32768
#define H_DIM 576
#define I_DIM 512
#define NEXP 8
#define WELEM 294912  // 576*512 elements per expert weight matrix
#define MAXMB 264     // per-phase max 128-row blocks (33792 rows >= 32768 + 8*127)

typedef __attribute__((ext_vector_type(8))) short short8;
typedef __attribute__((ext_vector_type(4))) float f32x4;
typedef __attribute__((ext_vector_type(4))) float f4;
typedef __attribute__((ext_vector_type(4))) unsigned short u16x4;

__device__ __forceinline__ unsigned short f2bf(float f) {
  union { float f; unsigned u; } v; v.f = f;
  unsigned r = (v.u + 0x7fffu + ((v.u >> 16) & 1u)) >> 16;
  return (unsigned short)r;
}

__device__ __forceinline__ void gl16(const void* g, void* l) {
  __builtin_amdgcn_global_load_lds(
      (const __attribute__((address_space(1))) unsigned*)g,
      (__attribute__((address_space(3))) unsigned*)l, 16, 0, 0);
}

// ---------------- conversions ----------------

__global__ void cvt_x_k(const float* __restrict__ x, unsigned short* __restrict__ xb) {
  size_t i = ((size_t)blockIdx.x * blockDim.x + threadIdx.x) * 4;
  f4 v = *(const f4*)(x + i);
  u16x4 o;
  o.x = f2bf(v.x); o.y = f2bf(v.y); o.z = f2bf(v.z); o.w = f2bf(v.w);
  *(u16x4*)(xb + i) = o;
}

// [576][512] fp32 -> [512][576] bf16, 18 slices: z0=sgw z1=suw z2-9=rgw z10-17=ruw
__global__ void cvt_HI_k(const float* __restrict__ sgw, const float* __restrict__ suw,
                         const float* __restrict__ rgw, const float* __restrict__ ruw,
                         unsigned short* __restrict__ wsg, unsigned short* __restrict__ wsu,
                         unsigned short* __restrict__ wrg, unsigned short* __restrict__ wru) {
  __shared__ float tile[32][33];
  int z = blockIdx.z;
  const float* src; unsigned short* dst;
  if (z == 0)      { src = sgw;                          dst = wsg; }
  else if (z == 1) { src = suw;                          dst = wsu; }
  else if (z < 10) { src = rgw + (size_t)(z - 2) * WELEM;  dst = wrg + (size_t)(z - 2) * WELEM; }
  else             { src = ruw + (size_t)(z - 10) * WELEM; dst = wru + (size_t)(z - 10) * WELEM; }
  const int R = 576, C = 512;
  int r0 = blockIdx.y * 32, c0 = blockIdx.x * 32;
  for (int i = threadIdx.y; i < 32; i += 8) {
    int r = r0 + i, c = c0 + threadIdx.x;
    tile[i][threadIdx.x] = (r < R) ? src[(size_t)r * C + c] : 0.f;
  }
  __syncthreads();
  for (int i = threadIdx.y; i < 32; i += 8) {
    int c = c0 + i, r = r0 + threadIdx.x;
    if (r < R) dst[(size_t)c * R + r] = f2bf(tile[threadIdx.x][i]);
  }
}

// [512][576] fp32 -> [576][512] bf16, 9 slices: z0=sdw z1-8=rdw
__global__ void cvt_IH_k(const float* __restrict__ sdw, const float* __restrict__ rdw,
                         unsigned short* __restrict__ wsd, unsigned short* __restrict__ wrd) {
  __shared__ float tile[32][33];
  int z = blockIdx.z;
  const float* src = (z == 0) ? sdw : rdw + (size_t)(z - 1) * WELEM;
  unsigned short* dst = (z == 0) ? wsd : wrd + (size_t)(z - 1) * WELEM;
  const int R = 512, C = 576;
  int r0 = blockIdx.y * 32, c0 = blockIdx.x * 32;
  for (int i = threadIdx.y; i < 32; i += 8) {
    int r = r0 + i, c = c0 + threadIdx.x;
    tile[i][threadIdx.x] = (c < C) ? src[(size_t)r * C + c] : 0.f;
  }
  __syncthreads();
  for (int i = threadIdx.y; i < 32; i += 8) {
    int c = c0 + i, r = r0 + threadIdx.x;
    if (c < C) dst[(size_t)c * R + r] = f2bf(tile[threadIdx.x][i]);
  }
}

// ---------------- router (thread-per-token, block-aggregated atomics) --------
// 16 histogram segments: seg = k*8 + e (k=0 primary, k=1 secondary)

__global__ __launch_bounds__(256) void router_k(
    const float* __restrict__ x, const float* __restrict__ rw,
    const float* __restrict__ rb, int* __restrict__ tki,
    float* __restrict__ tkw, int* __restrict__ counts /*stride 32*/) {
  __shared__ float lrw[H_DIM * NEXP];
  __shared__ int hist[16];
  int tid = threadIdx.x;
  for (int i = tid; i < H_DIM * NEXP / 4; i += 256)
    *(f4*)&lrw[i * 4] = *(const f4*)&rw[i * 4];
  if (tid < 16) hist[tid] = 0;
  __syncthreads();

  int t = blockIdx.x * 256 + tid;
  const float* xr = x + (size_t)t * H_DIM;
  float acc[NEXP];
#pragma unroll
  for (int e = 0; e < NEXP; e++) acc[e] = 0.f;
  for (int h = 0; h < H_DIM; h += 4) {
    f4 xv = *(const f4*)(xr + h);
#pragma unroll
    for (int j = 0; j < 4; j++) {
      f4 w0 = *(const f4*)&lrw[(h + j) * NEXP];
      f4 w1 = *(const f4*)&lrw[(h + j) * NEXP + 4];
      float xs = xv[j];
      acc[0] += xs * w0.x; acc[1] += xs * w0.y;
      acc[2] += xs * w0.z; acc[3] += xs * w0.w;
      acc[4] += xs * w1.x; acc[5] += xs * w1.y;
      acc[6] += xs * w1.z; acc[7] += xs * w1.w;
    }
  }
#pragma unroll
  for (int e = 0; e < NEXP; e++) acc[e] += rb[e];
  int e0 = 0;
#pragma unroll
  for (int e = 1; e < NEXP; e++) if (acc[e] > acc[e0]) e0 = e;
  int e1 = -1;
#pragma unroll
  for (int e = 0; e < NEXP; e++) {
    if (e == e0) continue;
    if (e1 < 0 || acc[e] > acc[e1]) e1 = e;
  }
  float w0 = 1.f / (1.f + __expf(acc[e1] - acc[e0]));
  tki[t * 2] = e0; tki[t * 2 + 1] = e1;
  tkw[t * 2] = w0; tkw[t * 2 + 1] = 1.f - w0;
  atomicAdd(&hist[e0], 1);
  atomicAdd(&hist[8 + e1], 1);
  __syncthreads();
  if (tid < 16) atomicAdd(&counts[tid * 32], hist[tid]);
}

__global__ void offsets_k(const int* __restrict__ counts, int* __restrict__ offs16,
                          int* __restrict__ pcnt16, int* __restrict__ pinfo) {
  if (threadIdx.x == 0) {
    int o = 0;
    for (int s = 0; s < 16; s++) {
      int c = counts[s * 32];
      int pc = (c + 127) & ~127;
      offs16[s] = o; pcnt16[s] = pc;
      o += pc;
    }
    pinfo[0] = offs16[8];      // phase-0 rows (== phase-1 base)
    pinfo[1] = o - offs16[8];  // phase-1 rows
  }
}

// block-reserved scatter into 16-segment layout
__global__ __launch_bounds__(256) void scatter_k(
    const int* __restrict__ tki, const float* __restrict__ tkw,
    const int* __restrict__ offs16, int* __restrict__ cursor /*stride 32*/,
    int* __restrict__ etok, float* __restrict__ ew) {
  __shared__ int hist[16], base[16], lcur[16];
  int tid = threadIdx.x;
  if (tid < 16) { hist[tid] = 0; lcur[tid] = 0; }
  __syncthreads();
  int t = blockIdx.x * 256 + tid;
  int s0 = tki[t * 2], s1 = 8 + tki[t * 2 + 1];
  atomicAdd(&hist[s0], 1);
  atomicAdd(&hist[s1], 1);
  __syncthreads();
  if (tid < 16) base[tid] = atomicAdd(&cursor[tid * 32], hist[tid]);
  __syncthreads();
#pragma unroll
  for (int k = 0; k < 2; k++) {
    int s = (k == 0) ? s0 : s1;
    int r = atomicAdd(&lcur[s], 1);
    int slot = offs16[s] + base[s] + r;
    etok[slot] = t;
    ew[slot] = tkw[t * 2 + k];
  }
}

// ---------------- fused gate/up GEMM + silu ----------------
// SHARED=1: identity rows over all T tokens. SHARED=0: batched over one k-phase;
// segments padded to 128 rows => each block lies in exactly one segment.
template <int SHARED>
__global__ __launch_bounds__(512, 2) void gateup_k(
    const unsigned short* __restrict__ xb, const unsigned short* __restrict__ wg,
    const unsigned short* __restrict__ wu, unsigned short* __restrict__ h,
    const int* __restrict__ etok, const int* __restrict__ offs16,
    const int* __restrict__ pcnt16, const int* __restrict__ pinfo, int p) {
  int mb = blockIdx.x;
  int nrows = SHARED ? T_TOK : pinfo[p];
  if (mb * 128 >= nrows) return;
  int row_lo = (SHARED || p == 0) ? 0 : pinfo[0];
  int nb = blockIdx.y;
  __shared__ unsigned short As[128 * 32];
  __shared__ unsigned short Bg[128 * 32];
  __shared__ unsigned short Bu[128 * 32];
  int t = threadIdx.x;
  int wv = t >> 6, lane = t & 63;
  int ar = t >> 2, seg = t & 3;
  int sg = seg ^ ((ar >> 1) & 3);  // swizzled source segment
  int m0 = mb * 128 + ar;          // phase-local row
  int tok0, e = 0;
  if (SHARED) {
    tok0 = m0;
  } else {
    int g = row_lo + m0;
    int s = 0;
#pragma unroll
    for (int i = 0; i < 15; i++) s += (g >= offs16[i] + pcnt16[i]) ? 1 : 0;
    e = s & 7;
    tok0 = etok[g];
    if (tok0 < 0) tok0 = 0;
  }
  const unsigned short* ga = xb + (size_t)tok0 * H_DIM + sg * 8;
  int n0 = nb * 128 + ar;  // I-col, < 512 always
  const unsigned short* gg = wg + (size_t)e * WELEM + (size_t)n0 * H_DIM + sg * 8;
  const unsigned short* gu = wu + (size_t)e * WELEM + (size_t)n0 * H_DIM + sg * 8;
  char* lA = (char*)As + wv * 1024;
  char* lG = (char*)Bg + wv * 1024;
  char* lU = (char*)Bu + wv * 1024;
  int fr = lane & 15, fq = lane >> 4;
  int wm = (wv >> 2) * 64, wn = (wv & 3) * 32;
  f32x4 accg[4][2] = {};
  f32x4 accu[4][2] = {};
  for (int k0 = 0; k0 < H_DIM; k0 += 32) {
    gl16(ga + k0, lA);
    gl16(gg + k0, lG);
    gl16(gu + k0, lU);
    __syncthreads();
    short8 a[4], g[2], u[2];
#pragma unroll
    for (int i = 0; i < 4; i++) {
      int r = wm + i * 16 + fr;
      a[i] = *(const short8*)&As[r * 32 + (fq ^ ((r >> 1) & 3)) * 8];
    }
#pragma unroll
    for (int j = 0; j < 2; j++) {
      int r = wn + j * 16 + fr;
      int sw = (fq ^ ((r >> 1) & 3)) * 8;
      g[j] = *(const short8*)&Bg[r * 32 + sw];
      u[j] = *(const short8*)&Bu[r * 32 + sw];
    }
#pragma unroll
    for (int i = 0; i < 4; i++)
#pragma unroll
      for (int j = 0; j < 2; j++) {
        accg[i][j] = __builtin_amdgcn_mfma_f32_16x16x32_bf16(a[i], g[j], accg[i][j], 0, 0, 0);
        accu[i][j] = __builtin_amdgcn_mfma_f32_16x16x32_bf16(a[i], u[j], accu[i][j], 0, 0, 0);
      }
    __syncthreads();
  }
#pragma unroll
  for (int i = 0; i < 4; i++)
#pragma unroll
    for (int j = 0; j < 2; j++)
#pragma unroll
      for (int r = 0; r < 4; r++) {
        int row = mb * 128 + wm + i * 16 + fq * 4 + r;
        int col = nb * 128 + wn + j * 16 + fr;
        float gv = accg[i][j][r], uv = accu[i][j][r];
        float hv = (gv / (1.f + __expf(-gv))) * uv;
        h[(size_t)row * I_DIM + col] = f2bf(hv);
      }
}

// ---------------- down GEMM ----------------
// MODE 0: shared expert, direct store. MODE 1: one k-phase, non-atomic
// scatter-add (each token appears exactly once per phase => race-free).
template <int MODE>
__global__ __launch_bounds__(512, 2) void down_k(
    const unsigned short* __restrict__ hbuf, const unsigned short* __restrict__ wd,
    float* __restrict__ out, const int* __restrict__ etok, const float* __restrict__ ew,
    const int* __restrict__ offs16, const int* __restrict__ pcnt16,
    const int* __restrict__ pinfo, int p) {
  int mb = blockIdx.x;
  int nrows = (MODE == 0) ? T_TOK : pinfo[p];
  if (mb * 128 >= nrows) return;
  int row_lo = (MODE == 0 || p == 0) ? 0 : pinfo[0];
  int nb = blockIdx.y;
  __shared__ unsigned short As[128 * 32];
  __shared__ unsigned short Bs[128 * 32];
  int t = threadIdx.x;
  int wv = t >> 6, lane = t & 63;
  int ar = t >> 2, seg = t & 3;
  int sg = seg ^ ((ar >> 1) & 3);
  int e = 0;
  if (MODE == 1) {
    int g = row_lo + mb * 128 + ar;
    int s = 0;
#pragma unroll
    for (int i = 0; i < 15; i++) s += (g >= offs16[i] + pcnt16[i]) ? 1 : 0;
    e = s & 7;
  }
  const unsigned short* ga = hbuf + (size_t)(mb * 128 + ar) * I_DIM + sg * 8;
  int n0 = nb * 128 + ar;
  if (n0 > H_DIM - 1) n0 = H_DIM - 1;
  const unsigned short* gb = wd + (size_t)e * WELEM + (size_t)n0 * I_DIM + sg * 8;
  char* lA = (char*)As + wv * 1024;
  char* lB = (char*)Bs + wv * 1024;
  int fr = lane & 15, fq = lane >> 4;
  int wm = (wv >> 2) * 64, wn = (wv & 3) * 32;
  f32x4 acc[4][2] = {};
  for (int k0 = 0; k0 < I_DIM; k0 += 32) {
    gl16(ga + k0, lA);
    gl16(gb + k0, lB);
    __syncthreads();
    short8 a[4], b[2];
#pragma unroll
    for (int i = 0; i < 4; i++) {
      int r = wm + i * 16 + fr;
      a[i] = *(const short8*)&As[r * 32 + (fq ^ ((r >> 1) & 3)) * 8];
    }
#pragma unroll
    for (int j = 0; j < 2; j++) {
      int r = wn + j * 16 + fr;
      b[j] = *(const short8*)&Bs[r * 32 + (fq ^ ((r >> 1) & 3)) * 8];
    }
#pragma unroll
    for (int i = 0; i < 4; i++)
#pragma unroll
      for (int j = 0; j < 2; j++)
        acc[i][j] = __builtin_amdgcn_mfma_f32_16x16x32_bf16(a[i], b[j], acc[i][j], 0, 0, 0);
    __syncthreads();
  }
#pragma unroll
  for (int i = 0; i < 4; i++)
#pragma unroll
    for (int j = 0; j < 2; j++)
#pragma unroll
      for (int r = 0; r < 4; r++) {
        int mloc = mb * 128 + wm + i * 16 + fq * 4 + r;
        int col = nb * 128 + wn + j * 16 + fr;
        if (col >= H_DIM) continue;
        float v = acc[i][j][r];
        if (MODE == 0) {
          out[(size_t)mloc * H_DIM + col] = v;
        } else {
          int g = row_lo + mloc;
          int tok = etok[g];
          if (tok >= 0) out[(size_t)tok * H_DIM + col] += ew[g] * v;
        }
      }
}

// ---------------- host ----------------

extern "C" void kernel_launch(void* const* d_in, const int* in_sizes, int n_in,
                              void* d_out, int out_size, void* d_ws, size_t ws_size,
                              hipStream_t stream) {
  const float* x = (const float*)d_in[0];
  const float* sgw = (const float*)d_in[1];
  const float* suw = (const float*)d_in[2];
  const float* sdw = (const float*)d_in[3];
  const float* rgw = (const float*)d_in[4];
  const float* ruw = (const float*)d_in[5];
  const float* rdw = (const float*)d_in[6];
  const float* rw = (const float*)d_in[7];
  const float* rb = (const float*)d_in[8];
  float* out = (float*)d_out;
  char* ws = (char*)d_ws;

  const size_t o_xbf = 0;                       // 37,748,736
  const size_t o_w = 37748736;
  const size_t w_sg = o_w;
  const size_t w_su = o_w + 589824;
  const size_t w_sd = o_w + 1179648;
  const size_t w_rg = o_w + 1769472;
  const size_t w_ru = o_w + 6488064;
  const size_t w_rd = o_w + 11206656;
  const size_t o_tki = o_w + 15925248;          // 53,673,984
  const size_t o_tkw = o_tki + 262144;
  const size_t o_meta = o_tkw + 262144;         // 8 KB
  const size_t o_etok = o_meta + 8192;          // 67584*4
  const size_t o_ew = o_etok + 270336;
  const size_t o_h = o_ew + 270336;             // 33792 rows * 1024 B = 34,603,008
  // total = 89,350,144 bytes (< 105.3 MB proven available)

  unsigned short* xb = (unsigned short*)(ws + o_xbf);
  int* tki = (int*)(ws + o_tki);
  float* tkw = (float*)(ws + o_tkw);
  int* counts = (int*)(ws + o_meta);            // 16 x stride-32
  int* cursor = counts + 512;                   // 16 x stride-32
  int* offs16 = counts + 1024;
  int* pcnt16 = counts + 1040;
  int* pinfo = counts + 1056;
  int* etok = (int*)(ws + o_etok);
  float* ew = (float*)(ws + o_ew);
  unsigned short* h = (unsigned short*)(ws + o_h);

  hipMemsetAsync(ws + o_meta, 0, 8192, stream);
  hipMemsetAsync(etok, 0xFF, 270336, stream);   // pad tokens = -1
  hipMemsetAsync(ew, 0, 270336, stream);

  cvt_x_k<<<18432, 256, 0, stream>>>(x, xb);
  dim3 tb(32, 8);
  cvt_HI_k<<<dim3(16, 18, 18), tb, 0, stream>>>(
      sgw, suw, rgw, ruw,
      (unsigned short*)(ws + w_sg), (unsigned short*)(ws + w_su),
      (unsigned short*)(ws + w_rg), (unsigned short*)(ws + w_ru));
  cvt_IH_k<<<dim3(18, 16, 9), tb, 0, stream>>>(
      sdw, rdw, (unsigned short*)(ws + w_sd), (unsigned short*)(ws + w_rd));

  router_k<<<128, 256, 0, stream>>>(x, rw, rb, tki, tkw, counts);
  offsets_k<<<1, 64, 0, stream>>>(counts, offs16, pcnt16, pinfo);
  scatter_k<<<128, 256, 0, stream>>>(tki, tkw, offs16, cursor, etok, ew);

  // shared expert
  gateup_k<1><<<dim3(256, 4), 512, 0, stream>>>(
      xb, (unsigned short*)(ws + w_sg), (unsigned short*)(ws + w_su), h,
      nullptr, nullptr, nullptr, nullptr, 0);
  down_k<0><<<dim3(256, 5), 512, 0, stream>>>(
      h, (unsigned short*)(ws + w_sd), out, nullptr, nullptr, nullptr, nullptr,
      nullptr, 0);

  // routed experts: one gate/up + one down per k-phase (race-free RMW)
  for (int p = 0; p < 2; p++) {
    gateup_k<0><<<dim3(MAXMB, 4), 512, 0, stream>>>(
        xb, (unsigned short*)(ws + w_rg), (unsigned short*)(ws + w_ru), h,
        etok, offs16, pcnt16, pinfo, p);
    down_k<1><<<dim3(MAXMB, 5), 512, 0, stream>>>(
        h, (unsigned short*)(ws + w_rd), out, etok, ew, offs16, pcnt16, pinfo, p);
  }
}